// Round 1
// baseline (67641.016 us; speedup 1.0000x reference)
//
#include <hip/hip_runtime.h>
#include <math.h>

// Problem constants
#define BB 128      // batch
#define RR 512      // hidden
#define NSTEP 255   // T-1 sequential steps
// units: 0=fwd layer0, 1=bwd layer0, 2=fwd layer1, 3=bwd layer1
// Pipelining: at wave t, layer0 computes h0[t] (t in [0,254]); layer1 computes
// h1[t-1] (t in [1,255]) using h0[t-1] written by the previous wave.
// h-states are double buffered by wave parity: read parity t&1, write (t+1)&1.

struct StepP {
  const float* data;   // (256,128,65)
  const float* gt;     // (256,128,64)
  const float* Wi[4];  // (1536, xdim)
  const float* Wh[4];  // (1536, 512)
  const float* bi[4];  // (1536,)
  const float* bh[4];  // (1536,)
  float* hstate;       // 8 buffers of (128,512): unit*2 + parity
  float* Hs;           // (255,128,512) forward layer1 outputs
  float* Ss;           // (255,128,512) backward layer1 outputs (reversed-seq order)
};

__device__ __forceinline__ float sigmoidf_(float x) {
  return 1.0f / (1.0f + expf(-x));
}

__global__ __launch_bounds__(256)
void step_kernel(StepP p, int t) {
  const int unit = blockIdx.x >> 6;   // 4 units x 64 blocks
  const int rem  = blockIdx.x & 63;
  const int jb   = rem >> 2;          // 16 j-tiles of 32
  const int bb   = rem & 3;           // 4 b-tiles of 32
  const bool l1  = (unit >= 2);
  if (!l1 && t >= NSTEP) return;      // layer0 active for t in [0,254]
  if ( l1 && t < 1) return;           // layer1 active for t in [1,255]
  const int s = l1 ? (t - 1) : t;

  const float* Wi = p.Wi[unit];
  const float* Wh = p.Wh[unit];
  const float* bi = p.bi[unit];
  const float* bh = p.bh[unit];
  const int xdim = (unit == 0) ? 64 : (unit == 1 ? 65 : 512);
  const float* x;
  if (unit == 0)      x = p.gt   + (size_t)s * BB * 64;          // ground_truth[s]
  else if (unit == 1) x = p.data + (size_t)(255 - s) * BB * 65;  // xs_back[s] = data[255-s]
  else                x = p.hstate + (size_t)((unit - 2) * 2 + (t & 1)) * BB * RR; // h0[s]
  const float* hprev = p.hstate + (size_t)(unit * 2 + (t & 1)) * BB * RR;
  float* hnew        = p.hstate + (size_t)(unit * 2 + ((t + 1) & 1)) * BB * RR;
  float* seqout = (unit == 2) ? p.Hs + (size_t)s * BB * RR
                : (unit == 3) ? p.Ss + (size_t)s * BB * RR : (float*)0;

  __shared__ float lA [32][33];
  __shared__ float lW [3][32][33];
  __shared__ float lA2[32][33];
  __shared__ float lW2[3][32][33];

  const int tid = threadIdx.x;
  const int jj  = tid & 31;
  const int bq  = tid >> 5;            // 0..7, each handles 4 consecutive b
  const int j   = jb * 32 + jj;        // output column in [0,512)
  const int b0  = bb * 32;

  float ahr[4], ahz[4], ahn[4], air[4], aiz[4], ain[4];
  {
    const float br_ = bh[j], bz_ = bh[j + 512], bn_ = bh[j + 1024];
    const float cr_ = bi[j], cz_ = bi[j + 512], cn_ = bi[j + 1024];
    #pragma unroll
    for (int q = 0; q < 4; ++q) {
      ahr[q] = br_; ahz[q] = bz_; ahn[q] = bn_;
      air[q] = cr_; aiz[q] = cz_; ain[q] = cn_;
    }
  }

  // Main K=512 chunked loop: gh for all units; gi too when l1 (K=512).
  for (int kc = 0; kc < 512; kc += 32) {
    for (int i = tid; i < 1024; i += 256) {
      int row = i >> 5, col = i & 31;
      lA[row][col] = hprev[(size_t)(b0 + row) * RR + kc + col];
      if (l1) lA2[row][col] = x[(size_t)(b0 + row) * RR + kc + col];
    }
    #pragma unroll
    for (int g = 0; g < 3; ++g)
      for (int i = tid; i < 1024; i += 256) {
        int row = i >> 5, col = i & 31;
        lW[g][row][col] = Wh[(size_t)(g * RR + jb * 32 + row) * RR + kc + col];
        if (l1) lW2[g][row][col] = Wi[(size_t)(g * RR + jb * 32 + row) * RR + kc + col];
      }
    __syncthreads();
    for (int k = 0; k < 32; ++k) {
      float wr = lW[0][jj][k], wz = lW[1][jj][k], wn = lW[2][jj][k];
      float vr = 0.f, vz = 0.f, vn = 0.f;
      if (l1) { vr = lW2[0][jj][k]; vz = lW2[1][jj][k]; vn = lW2[2][jj][k]; }
      #pragma unroll
      for (int q = 0; q < 4; ++q) {
        float a = lA[bq * 4 + q][k];
        ahr[q] = fmaf(a, wr, ahr[q]);
        ahz[q] = fmaf(a, wz, ahz[q]);
        ahn[q] = fmaf(a, wn, ahn[q]);
        if (l1) {
          float a2 = lA2[bq * 4 + q][k];
          air[q] = fmaf(a2, vr, air[q]);
          aiz[q] = fmaf(a2, vz, aiz[q]);
          ain[q] = fmaf(a2, vn, ain[q]);
        }
      }
    }
    __syncthreads();
  }

  // Layer0 input projection: small K (64/65), read x and Wi straight from cache.
  if (!l1) {
    for (int k = 0; k < xdim; ++k) {
      float wr = Wi[(size_t)(0 * RR + j) * xdim + k];
      float wz = Wi[(size_t)(1 * RR + j) * xdim + k];
      float wn = Wi[(size_t)(2 * RR + j) * xdim + k];
      #pragma unroll
      for (int q = 0; q < 4; ++q) {
        float xa = x[(size_t)(b0 + bq * 4 + q) * xdim + k];
        air[q] = fmaf(xa, wr, air[q]);
        aiz[q] = fmaf(xa, wz, aiz[q]);
        ain[q] = fmaf(xa, wn, ain[q]);
      }
    }
  }

  // GRU gate fusion + state write
  #pragma unroll
  for (int q = 0; q < 4; ++q) {
    const int b = b0 + bq * 4 + q;
    float hp = hprev[(size_t)b * RR + j];
    float r  = sigmoidf_(air[q] + ahr[q]);
    float z  = sigmoidf_(aiz[q] + ahz[q]);
    float n  = tanhf(ain[q] + r * ahn[q]);
    float h  = (1.0f - z) * n + z * hp;
    hnew[(size_t)b * RR + j] = h;
    if (seqout) seqout[(size_t)b * RR + j] = h;
  }
}

// dec_t = relu([H, hb_used] @ dec_W^T + dec_b); M=32640, N=512, K=1024
__global__ __launch_bounds__(256)
void dec_kernel(const float* __restrict__ Hs, const float* __restrict__ Ss,
                const float* __restrict__ decW, const float* __restrict__ decb,
                float* __restrict__ dect) {
  const int mb = blockIdx.x;   // 510
  const int nb = blockIdx.y;   // 8
  const int r0 = mb * 64, n0 = nb * 64;
  __shared__ float sA[64][33];
  __shared__ float sB[32][65];
  const int tid = threadIdx.x;
  const int tx = tid & 15, ty = tid >> 4;
  float acc[4][4] = {};
  for (int kc = 0; kc < 1024; kc += 32) {
    for (int i = tid; i < 64 * 32; i += 256) {
      int rl = i >> 5, kl = i & 31;
      int row = r0 + rl;
      int t = row >> 7, b = row & 127;
      int k = kc + kl;
      float v;
      if (k < 512) v = Hs[((size_t)t * BB + b) * RR + k];
      else {
        int kk = k - 512;
        v = (t <= 253) ? Ss[((size_t)(253 - t) * BB + b) * RR + kk] : 0.0f;  // hb_used
      }
      sA[rl][kl] = v;
    }
    for (int i = tid; i < 64 * 32; i += 256) {
      int nl = i >> 5, kl = i & 31;
      sB[kl][nl] = decW[(size_t)(n0 + nl) * 1024 + kc + kl];
    }
    __syncthreads();
    for (int kl = 0; kl < 32; ++kl) {
      float av[4], bv[4];
      #pragma unroll
      for (int q = 0; q < 4; ++q) av[q] = sA[ty * 4 + q][kl];
      #pragma unroll
      for (int pn = 0; pn < 4; ++pn) bv[pn] = sB[kl][tx * 4 + pn];
      #pragma unroll
      for (int q = 0; q < 4; ++q)
        #pragma unroll
        for (int pn = 0; pn < 4; ++pn)
          acc[q][pn] = fmaf(av[q], bv[pn], acc[q][pn]);
    }
    __syncthreads();
  }
  #pragma unroll
  for (int q = 0; q < 4; ++q)
    #pragma unroll
    for (int pn = 0; pn < 4; ++pn) {
      int row = r0 + ty * 4 + q;
      int n = n0 + tx * 4 + pn;
      dect[(size_t)row * 512 + n] = fmaxf(acc[q][pn] + decb[n], 0.0f);
    }
}

// mean = dec_t @ mean_W^T + mean_b; loss += (mean - gt[t+1])^2  (M=32640,N=64,K=512)
__global__ __launch_bounds__(256)
void mean_loss_kernel(const float* __restrict__ dect, const float* __restrict__ meanW,
                      const float* __restrict__ meanb, const float* __restrict__ gt,
                      float* __restrict__ out) {
  const int mb = blockIdx.x;  // 510
  const int r0 = mb * 64;
  __shared__ float sA[64][33];
  __shared__ float sB[32][65];
  __shared__ float red[256];
  const int tid = threadIdx.x;
  const int tx = tid & 15, ty = tid >> 4;
  float acc[4][4] = {};
  for (int kc = 0; kc < 512; kc += 32) {
    for (int i = tid; i < 64 * 32; i += 256) {
      int rl = i >> 5, kl = i & 31;
      sA[rl][kl] = dect[(size_t)(r0 + rl) * 512 + kc + kl];
    }
    for (int i = tid; i < 64 * 32; i += 256) {
      int nl = i >> 5, kl = i & 31;
      sB[kl][nl] = meanW[(size_t)nl * 512 + kc + kl];
    }
    __syncthreads();
    for (int kl = 0; kl < 32; ++kl) {
      float av[4], bv[4];
      #pragma unroll
      for (int q = 0; q < 4; ++q) av[q] = sA[ty * 4 + q][kl];
      #pragma unroll
      for (int pn = 0; pn < 4; ++pn) bv[pn] = sB[kl][tx * 4 + pn];
      #pragma unroll
      for (int q = 0; q < 4; ++q)
        #pragma unroll
        for (int pn = 0; pn < 4; ++pn)
          acc[q][pn] = fmaf(av[q], bv[pn], acc[q][pn]);
    }
    __syncthreads();
  }
  float lsum = 0.0f;
  #pragma unroll
  for (int q = 0; q < 4; ++q)
    #pragma unroll
    for (int pn = 0; pn < 4; ++pn) {
      int row = r0 + ty * 4 + q;
      int y = tx * 4 + pn;
      int t = row >> 7, b = row & 127;
      float m = acc[q][pn] + meanb[y];
      float d = m - gt[(size_t)(t + 1) * BB * 64 + b * 64 + y];
      lsum = fmaf(d, d, lsum);
    }
  red[tid] = lsum;
  __syncthreads();
  for (int s2 = 128; s2 > 0; s2 >>= 1) {
    if (tid < s2) red[tid] += red[tid + s2];
    __syncthreads();
  }
  if (tid == 0) atomicAdd(out, red[0] * (1.0f / (255.0f * 128.0f)));
}

extern "C" void kernel_launch(void* const* d_in, const int* in_sizes, int n_in,
                              void* d_out, int out_size, void* d_ws, size_t ws_size,
                              hipStream_t stream) {
  StepP p;
  p.data = (const float*)d_in[0];
  p.gt   = (const float*)d_in[1];
  // forward stack
  p.Wi[0] = (const float*)d_in[2];  p.Wh[0] = (const float*)d_in[3];
  p.bi[0] = (const float*)d_in[4];  p.bh[0] = (const float*)d_in[5];
  p.Wi[2] = (const float*)d_in[6];  p.Wh[2] = (const float*)d_in[7];
  p.bi[2] = (const float*)d_in[8];  p.bh[2] = (const float*)d_in[9];
  // backward stack
  p.Wi[1] = (const float*)d_in[10]; p.Wh[1] = (const float*)d_in[11];
  p.bi[1] = (const float*)d_in[12]; p.bh[1] = (const float*)d_in[13];
  p.Wi[3] = (const float*)d_in[14]; p.Wh[3] = (const float*)d_in[15];
  p.bi[3] = (const float*)d_in[16]; p.bh[3] = (const float*)d_in[17];
  const float* decW  = (const float*)d_in[18];
  const float* decb  = (const float*)d_in[19];
  const float* meanW = (const float*)d_in[20];
  const float* meanb = (const float*)d_in[21];

  // Workspace layout (floats):
  //   hstate: 8 * 128*512            =   524,288  (2.0 MB)
  //   Hs:     255*128*512            = 16,711,680 (66.8 MB)
  //   Ss:     255*128*512            = 16,711,680 (66.8 MB)
  //   dect:   32640*512              = 16,711,680 (66.8 MB)
  float* ws = (float*)d_ws;
  float* hstate = ws;
  float* Hs = hstate + (size_t)8 * BB * RR;
  float* Ss = Hs + (size_t)NSTEP * BB * RR;
  float* dect = Ss + (size_t)NSTEP * BB * RR;
  p.hstate = hstate; p.Hs = Hs; p.Ss = Ss;

  hipMemsetAsync(d_out, 0, sizeof(float), stream);
  hipMemsetAsync(hstate, 0, (size_t)8 * BB * RR * sizeof(float), stream);

  for (int t = 0; t < 256; ++t)
    step_kernel<<<dim3(256), dim3(256), 0, stream>>>(p, t);

  dec_kernel<<<dim3(510, 8), dim3(256), 0, stream>>>(Hs, Ss, decW, decb, dect);
  mean_loss_kernel<<<dim3(510), dim3(256), 0, stream>>>(dect, meanW, meanb,
                                                        p.gt, (float*)d_out);
}

// Round 3
// 5469.645 us; speedup vs baseline: 12.3666x; 12.3666x over previous
//
#include <hip/hip_runtime.h>
#include <math.h>

#define BB 128      // batch
#define RR 512      // hidden
#define NSTEP 255   // T-1 sequential steps

typedef __attribute__((ext_vector_type(8))) __bf16 bf16x8;
typedef __attribute__((ext_vector_type(4))) float f32x4;

__device__ __forceinline__ bf16x8 ld8(const ushort* p) {
  return *reinterpret_cast<const bf16x8*>(p);
}
__device__ __forceinline__ ushort bf16r(float x) {
  unsigned u = __float_as_uint(x);
  u += 0x7fffu + ((u >> 16) & 1u);
  return (ushort)(u >> 16);
}
__device__ __forceinline__ float fsig(float x) { return 1.0f / (1.0f + __expf(-x)); }
__device__ __forceinline__ float ftanh(float x) {
  float e = __expf(-2.0f * fabsf(x));
  float r = (1.0f - e) / (1.0f + e);
  return copysignf(r, x);
}

// units: 0=fwd L0, 1=bwd L0, 2=fwd L1, 3=bwd L1. Pipelined: at wave t, L0
// computes h0[t] (t in [0,254]); L1 computes h1[t-1] (t in [1,255]) from
// h0[t-1] written last wave. h double-buffered by parity.
struct SP {
  const ushort* gtb;     // (256,128,64) bf16 ground truth
  const ushort* xpad;    // (256,128,96) bf16 data padded 65->96
  const ushort* Whb[4];  // (1536,512) bf16
  const ushort* Wib[4];  // unit0:(1536,64) unit1:(1536,96 pad) units2,3:(1536,512)
  const float* bi[4];
  const float* bh[4];
  float*  hf;            // 8 x (128*512) fp32 master h  [unit*2+parity]
  ushort* hb;            // 8 x (128*512) bf16 mirror
  ushort* Hsb;           // (255,128,512) bf16 fwd L1 outputs
  ushort* Ssb;           // (255,128,512) bf16 bwd L1 outputs
};

__global__ __launch_bounds__(256)
void step_mfma(SP p, int t) {
  const int unit = blockIdx.x >> 6;       // 4 units x 64 blocks
  const int rem  = blockIdx.x & 63;
  const int jb   = rem >> 1;              // 32 j-tiles of 16
  const int mb   = rem & 1;               // 2 m-halves of 64
  const bool l1  = (unit >= 2);
  if (!l1 && t >= NSTEP) return;
  if ( l1 && t < 1) return;
  const int s = l1 ? (t - 1) : t;

  const int wave = threadIdx.x >> 6, lane = threadIdx.x & 63;
  const int m0 = mb * 64 + wave * 16;     // batch-row tile base
  const int j0 = jb * 16;                 // hidden-col tile base
  const int lr = lane & 15;
  const int kq = (lane >> 4) * 8;
  const int col = j0 + lr;

  const int rp = t & 1;
  const ushort* hprevb = p.hb + ((unit * 2 + rp) << 16);
  const float*  hprevf = p.hf + ((unit * 2 + rp) << 16);
  float*  hnewf = p.hf + ((unit * 2 + (rp ^ 1)) << 16);
  ushort* hnewb = p.hb + ((unit * 2 + (rp ^ 1)) << 16);

  // acc init with biases (r,z carry bi+bh; in carries bi_n; hn carries bh_n)
  f32x4 accR, accZ, accIN, accHN;
  {
    float r0 = p.bi[unit][col]        + p.bh[unit][col];
    float z0 = p.bi[unit][col + 512]  + p.bh[unit][col + 512];
    float i0 = p.bi[unit][col + 1024];
    float h0 = p.bh[unit][col + 1024];
    accR = (f32x4){r0, r0, r0, r0};
    accZ = (f32x4){z0, z0, z0, z0};
    accIN = (f32x4){i0, i0, i0, i0};
    accHN = (f32x4){h0, h0, h0, h0};
  }

  const ushort* Whb = p.Whb[unit];
  const ushort* aB = hprevb + (m0 + lr) * RR + kq;
  const ushort* bR = Whb + (size_t)(col)        * RR + kq;
  const ushort* bZ = Whb + (size_t)(col + 512)  * RR + kq;
  const ushort* bN = Whb + (size_t)(col + 1024) * RR + kq;
  const ushort* a2B = nullptr, *cR = nullptr, *cZ = nullptr, *cN = nullptr;
  if (l1) {
    a2B = p.hb + (((unit - 2) * 2 + rp) << 16) + (m0 + lr) * RR + kq;  // h0[s]
    const ushort* Wib = p.Wib[unit];
    cR = Wib + (size_t)(col)        * RR + kq;
    cZ = Wib + (size_t)(col + 512)  * RR + kq;
    cN = Wib + (size_t)(col + 1024) * RR + kq;
  }

  for (int kc = 0; kc < 512; kc += 32) {
    bf16x8 a  = ld8(aB + kc);
    bf16x8 wr = ld8(bR + kc), wz = ld8(bZ + kc), wn = ld8(bN + kc);
    accR  = __builtin_amdgcn_mfma_f32_16x16x32_bf16(a, wr, accR, 0, 0, 0);
    accZ  = __builtin_amdgcn_mfma_f32_16x16x32_bf16(a, wz, accZ, 0, 0, 0);
    accHN = __builtin_amdgcn_mfma_f32_16x16x32_bf16(a, wn, accHN, 0, 0, 0);
    if (l1) {
      bf16x8 a2 = ld8(a2B + kc);
      bf16x8 vr = ld8(cR + kc), vz = ld8(cZ + kc), vn = ld8(cN + kc);
      accR  = __builtin_amdgcn_mfma_f32_16x16x32_bf16(a2, vr, accR, 0, 0, 0);
      accZ  = __builtin_amdgcn_mfma_f32_16x16x32_bf16(a2, vz, accZ, 0, 0, 0);
      accIN = __builtin_amdgcn_mfma_f32_16x16x32_bf16(a2, vn, accIN, 0, 0, 0);
    }
  }

  if (!l1) {  // layer-0 input projection, small K (64 or 96 padded)
    const int xd = (unit == 0) ? 64 : 96;
    const ushort* x = (unit == 0) ? p.gtb + (size_t)s * BB * 64
                                  : p.xpad + (size_t)(255 - s) * BB * 96;
    const ushort* Wib = p.Wib[unit];
    const ushort* xA = x + (m0 + lr) * xd + kq;
    for (int kc = 0; kc < xd; kc += 32) {
      bf16x8 a  = ld8(xA + kc);
      bf16x8 vr = ld8(Wib + (size_t)(col)        * xd + kc + kq);
      bf16x8 vz = ld8(Wib + (size_t)(col + 512)  * xd + kc + kq);
      bf16x8 vn = ld8(Wib + (size_t)(col + 1024) * xd + kc + kq);
      accR  = __builtin_amdgcn_mfma_f32_16x16x32_bf16(a, vr, accR, 0, 0, 0);
      accZ  = __builtin_amdgcn_mfma_f32_16x16x32_bf16(a, vz, accZ, 0, 0, 0);
      accIN = __builtin_amdgcn_mfma_f32_16x16x32_bf16(a, vn, accIN, 0, 0, 0);
    }
  }

  ushort* seq = (unit == 2) ? p.Hsb + (size_t)s * BB * RR
              : (unit == 3) ? p.Ssb + (size_t)s * BB * RR : (ushort*)0;
  #pragma unroll
  for (int q = 0; q < 4; ++q) {
    const int row = m0 + (lane >> 4) * 4 + q;      // batch index
    float r = fsig(accR[q]);
    float z = fsig(accZ[q]);
    float n = ftanh(fmaf(r, accHN[q], accIN[q]));
    float hp = hprevf[row * RR + col];
    float h = fmaf(z, hp - n, n);                  // (1-z)n + z*hp
    hnewf[row * RR + col] = h;
    ushort hbv = bf16r(h);
    hnewb[row * RR + col] = hbv;
    if (seq) seq[row * RR + col] = hbv;
  }
}

// dec_t = relu([H, hb_used] @ dec_W^T + dec_b): M=255*128, N=512, K=1024
__global__ __launch_bounds__(256)
void dec_mfma(const ushort* __restrict__ Hsb, const ushort* __restrict__ Ssb,
              const ushort* __restrict__ decWb, const float* __restrict__ decb,
              ushort* __restrict__ dectb) {
  const int t  = blockIdx.x;          // 0..254 (M block = one timestep, 128 rows)
  const int nb = blockIdx.y;          // 0..7   (N block 64)
  const int wave = threadIdx.x >> 6, lane = threadIdx.x & 63;
  const int lr = lane & 15, kq = (lane >> 4) * 8;
  const int mrow = wave * 32;
  f32x4 acc[2][4] = {};
  for (int kc = 0; kc < 1024; kc += 32) {
    if (kc >= 512 && t == 254) break;   // hb_used[254] == 0
    const ushort* abase = (kc < 512)
        ? Hsb + ((size_t)t * BB) * RR + kc
        : Ssb + ((size_t)(253 - t) * BB) * RR + (kc - 512);
    bf16x8 a[2];
    #pragma unroll
    for (int mi = 0; mi < 2; ++mi)
      a[mi] = ld8(abase + (mrow + mi * 16 + lr) * RR + kq);
    bf16x8 bw[4];
    #pragma unroll
    for (int ni = 0; ni < 4; ++ni)
      bw[ni] = ld8(decWb + (size_t)(nb * 64 + ni * 16 + lr) * 1024 + kc + kq);
    #pragma unroll
    for (int mi = 0; mi < 2; ++mi)
      #pragma unroll
      for (int ni = 0; ni < 4; ++ni)
        acc[mi][ni] = __builtin_amdgcn_mfma_f32_16x16x32_bf16(a[mi], bw[ni], acc[mi][ni], 0, 0, 0);
  }
  #pragma unroll
  for (int mi = 0; mi < 2; ++mi)
    #pragma unroll
    for (int ni = 0; ni < 4; ++ni)
      #pragma unroll
      for (int q = 0; q < 4; ++q) {
        int row = t * BB + mrow + mi * 16 + (lane >> 4) * 4 + q;
        int n = nb * 64 + ni * 16 + lr;
        float v = fmaxf(acc[mi][ni][q] + decb[n], 0.0f);
        dectb[(size_t)row * 512 + n] = bf16r(v);
      }
}

// mean = dec_t @ mean_W^T + mean_b; loss += (mean - gt[t+1])^2
__global__ __launch_bounds__(256)
void mean_loss_mfma(const ushort* __restrict__ dectb, const ushort* __restrict__ meanWb,
                    const float* __restrict__ meanb, const float* __restrict__ gt,
                    float* __restrict__ out) {
  const int t = blockIdx.x;   // 0..254
  const int wave = threadIdx.x >> 6, lane = threadIdx.x & 63;
  const int lr = lane & 15, kq = (lane >> 4) * 8;
  const int mrow = wave * 32;
  f32x4 acc[2][4] = {};
  for (int kc = 0; kc < 512; kc += 32) {
    bf16x8 a[2];
    #pragma unroll
    for (int mi = 0; mi < 2; ++mi)
      a[mi] = ld8(dectb + ((size_t)t * BB + mrow + mi * 16 + lr) * 512 + kc + kq);
    bf16x8 bw[4];
    #pragma unroll
    for (int ni = 0; ni < 4; ++ni)
      bw[ni] = ld8(meanWb + (size_t)(ni * 16 + lr) * 512 + kc + kq);
    #pragma unroll
    for (int mi = 0; mi < 2; ++mi)
      #pragma unroll
      for (int ni = 0; ni < 4; ++ni)
        acc[mi][ni] = __builtin_amdgcn_mfma_f32_16x16x32_bf16(a[mi], bw[ni], acc[mi][ni], 0, 0, 0);
  }
  float lsum = 0.0f;
  #pragma unroll
  for (int mi = 0; mi < 2; ++mi)
    #pragma unroll
    for (int ni = 0; ni < 4; ++ni)
      #pragma unroll
      for (int q = 0; q < 4; ++q) {
        int b = mrow + mi * 16 + (lane >> 4) * 4 + q;
        int y = ni * 16 + lr;
        float m = acc[mi][ni][q] + meanb[y];
        float d = m - gt[(((size_t)(t + 1)) * BB + b) * 64 + y];
        lsum = fmaf(d, d, lsum);
      }
  __shared__ float red[256];
  red[threadIdx.x] = lsum;
  __syncthreads();
  for (int s2 = 128; s2 > 0; s2 >>= 1) {
    if (threadIdx.x < s2) red[threadIdx.x] += red[threadIdx.x + s2];
    __syncthreads();
  }
  if (threadIdx.x == 0) atomicAdd(out, red[0] * (1.0f / 32640.0f));
}

__global__ __launch_bounds__(256)
void cvt_bf16(const float* __restrict__ s, ushort* __restrict__ d, int n) {
  for (int i = blockIdx.x * 256 + threadIdx.x; i < n; i += gridDim.x * 256)
    d[i] = bf16r(s[i]);
}

__global__ __launch_bounds__(256)
void cvt_bf16_pad(const float* __restrict__ s, ushort* __restrict__ d,
                  int rows, int sc, int dc) {
  int n = rows * dc;
  for (int i = blockIdx.x * 256 + threadIdx.x; i < n; i += gridDim.x * 256) {
    int r = i / dc, c = i - r * dc;
    d[i] = (c < sc) ? bf16r(s[r * sc + c]) : (ushort)0;
  }
}

extern "C" void kernel_launch(void* const* d_in, const int* in_sizes, int n_in,
                              void* d_out, int out_size, void* d_ws, size_t ws_size,
                              hipStream_t stream) {
  const float* data = (const float*)d_in[0];
  const float* gt   = (const float*)d_in[1];
  const float* Wi[4] = {(const float*)d_in[2], (const float*)d_in[10],
                        (const float*)d_in[6], (const float*)d_in[14]};
  const float* Wh[4] = {(const float*)d_in[3], (const float*)d_in[11],
                        (const float*)d_in[7], (const float*)d_in[15]};
  const float* bi[4] = {(const float*)d_in[4], (const float*)d_in[12],
                        (const float*)d_in[8], (const float*)d_in[16]};
  const float* bh[4] = {(const float*)d_in[5], (const float*)d_in[13],
                        (const float*)d_in[9], (const float*)d_in[17]};
  const float* decW  = (const float*)d_in[18];
  const float* decb  = (const float*)d_in[19];
  const float* meanW = (const float*)d_in[20];
  const float* meanb = (const float*)d_in[21];

  // Workspace carve (all 16B aligned)
  char* w = (char*)d_ws;
  float* hf = (float*)w;                 w += (size_t)8 * BB * RR * 4;   // 2 MB
  ushort* hb = (ushort*)w;               w += (size_t)8 * BB * RR * 2;   // 1 MB
  ushort* Whb[4], *Wib[4];
  for (int u = 0; u < 4; ++u) { Whb[u] = (ushort*)w; w += (size_t)1536 * 512 * 2; }
  Wib[2] = (ushort*)w; w += (size_t)1536 * 512 * 2;
  Wib[3] = (ushort*)w; w += (size_t)1536 * 512 * 2;
  Wib[0] = (ushort*)w; w += (size_t)1536 * 64 * 2;
  Wib[1] = (ushort*)w; w += (size_t)1536 * 96 * 2;
  ushort* gtb   = (ushort*)w; w += (size_t)256 * BB * 64 * 2;
  ushort* xpad  = (ushort*)w; w += (size_t)256 * BB * 96 * 2;
  ushort* Hsb   = (ushort*)w; w += (size_t)NSTEP * BB * RR * 2;
  ushort* Ssb   = (ushort*)w; w += (size_t)NSTEP * BB * RR * 2;
  ushort* dectb = (ushort*)w; w += (size_t)NSTEP * BB * 512 * 2;
  ushort* decWb = (ushort*)w; w += (size_t)512 * 1024 * 2;
  ushort* meanWb = (ushort*)w; w += (size_t)64 * 512 * 2;

  hipMemsetAsync(d_out, 0, sizeof(float), stream);
  hipMemsetAsync(hf, 0, (size_t)8 * BB * RR * 4, stream);
  hipMemsetAsync(hb, 0, (size_t)8 * BB * RR * 2, stream);

  // Upfront bf16 conversions
  for (int u = 0; u < 4; ++u)
    cvt_bf16<<<512, 256, 0, stream>>>(Wh[u], Whb[u], 1536 * 512);
  cvt_bf16<<<512, 256, 0, stream>>>(Wi[2], Wib[2], 1536 * 512);
  cvt_bf16<<<512, 256, 0, stream>>>(Wi[3], Wib[3], 1536 * 512);
  cvt_bf16<<<512, 256, 0, stream>>>(Wi[0], Wib[0], 1536 * 64);
  cvt_bf16_pad<<<512, 256, 0, stream>>>(Wi[1], Wib[1], 1536, 65, 96);
  cvt_bf16<<<512, 256, 0, stream>>>(gt, gtb, 256 * BB * 64);
  cvt_bf16_pad<<<512, 256, 0, stream>>>(data, xpad, 256 * BB, 65, 96);
  cvt_bf16<<<512, 256, 0, stream>>>(decW, decWb, 512 * 1024);
  cvt_bf16<<<512, 256, 0, stream>>>(meanW, meanWb, 64 * 512);

  SP p;
  p.gtb = gtb; p.xpad = xpad;
  for (int u = 0; u < 4; ++u) {
    p.Whb[u] = Whb[u]; p.Wib[u] = Wib[u]; p.bi[u] = bi[u]; p.bh[u] = bh[u];
  }
  p.hf = hf; p.hb = hb; p.Hsb = Hsb; p.Ssb = Ssb;

  for (int t = 0; t < 256; ++t)
    step_mfma<<<dim3(256), dim3(256), 0, stream>>>(p, t);

  dec_mfma<<<dim3(255, 8), dim3(256), 0, stream>>>(Hsb, Ssb, decWb, decb, dectb);
  mean_loss_mfma<<<dim3(255), dim3(256), 0, stream>>>(dectb, meanWb, meanb, gt,
                                                      (float*)d_out);
}